// Round 18
// baseline (18.263 us; speedup 1.0000x reference)
//
#include <hip/hip_runtime.h>
#include <math.h>

#define L 512
#define NTHREADS 256
#define BLOCK_TT 64       // four 16-t sub-tiles; shared prologue AND shared B-gather
#define ZWIN 9.0f         // dropped pdf mass <= exp(-40.5): < 1e-10 effect on output
#define NXCD 8

typedef __attribute__((ext_vector_type(8))) short bf16x8;
typedef __attribute__((ext_vector_type(4))) float f32x4;

static constexpr float EPS = 1e-6f;
static constexpr float INV_SQRT_2PI = 0.39894228040143267794f;

union BFrag { unsigned int u[4]; bf16x8 h; };

__global__ __launch_bounds__(NTHREADS, 2) void ge_mfma(
    const int*   __restrict__ durs,  // [B, L]
    const float* __restrict__ text,  // [B, L, 256]
    float*       __restrict__ out,   // [B, T, 256]
    int B, int T, int tilesPerB, int nwg)
{
    __shared__ float2 s_mi[L];

    const int tid  = threadIdx.x;
    const int lane = tid & 63;
    const int wid  = tid >> 6;
    const int g    = lane >> 4;      // k-group (A/B), C row-group
    const int mrow = lane & 15;      // A-row (t offset) == B/C-col (d offset)

    const int orig = blockIdx.x;
    const int wg   = (nwg % NXCD == 0) ? (orig & (NXCD - 1)) * (nwg / NXCD) + (orig >> 3)
                                       : orig;
    const int b      = wg / tilesPerB;
    const int tbase0 = (wg % tilesPerB) * BLOCK_TT;

    // ---- wave-private scan, once per block: lane owns rows 8*lane..8*lane+7 ----
    const int r0 = lane << 3;
    const int4 da = ((const int4*)(durs + (size_t)b * L + r0))[0];
    const int4 db = ((const int4*)(durs + (size_t)b * L + r0))[1];
    int dv[8] = {da.x, da.y, da.z, da.w, db.x, db.y, db.z, db.w};
    int cs[8];
    int run = 0;
    #pragma unroll
    for (int j = 0; j < 8; ++j) { run += dv[j]; cs[j] = run; }
    int v = run;
    #pragma unroll
    for (int off = 1; off < 64; off <<= 1) {
        int n = __shfl_up(v, off, 64);
        if (lane >= off) v += n;
    }
    const int excl = v - run;

    // ---- params to LDS + UNION band over the 64-t block ----
    const float tlo = (float)tbase0 + 0.5f;
    const float thi = (float)tbase0 + (float)BLOCK_TT - 0.5f;
    int mn = L, mx = -1;
    #pragma unroll
    for (int j = 0; j < 8; ++j) {
        const float d  = (float)dv[j];
        const float m  = (float)(cs[j] + excl) + 0.5f * d;
        const float sg = 0.5f * d + EPS;
        s_mi[r0 + j] = make_float2(m, 1.0f / sg);
        const float r = ZWIN * sg;
        if (dv[j] >= 1 && m + r >= tlo && m - r <= thi) {
            mn = min(mn, r0 + j);
            mx = max(mx, r0 + j);
        }
    }
    #pragma unroll
    for (int off = 32; off > 0; off >>= 1) {
        mn = min(mn, __shfl_xor(mn, off, 64));
        mx = max(mx, __shfl_xor(mx, off, 64));
    }
    asm volatile("s_waitcnt lgkmcnt(0)" ::: "memory");   // own-wave s_mi writes -> reads
    __builtin_amdgcn_sched_barrier(0);

    // ---- main loop over union band: ONE B-gather feeds FOUR 16-t halves ----
    f32x4 acc[4][4];                 // [half][nt]
    float ps[4] = {0.f, 0.f, 0.f, 0.f};
    #pragma unroll
    for (int h = 0; h < 4; ++h)
        #pragma unroll
        for (int nt = 0; nt < 4; ++nt)
            acc[h][nt] = (f32x4){0.f, 0.f, 0.f, 0.f};

    const float tf0 = (float)(tbase0 + mrow) + 0.5f;
    const float* tbp = text + (size_t)b * L * 256 + (wid << 6) + mrow;

    for (int kb = (mn & ~7); kb <= mx; kb += 32) {
        const int k0 = kb + (g << 3);

        // A fragments for 4 halves; psum on fp32 pre-round
        BFrag A[4];
        #pragma unroll
        for (int jp = 0; jp < 4; ++jp) {
            const int ka = k0 + 2 * jp;
            const int kc = ka + 1;
            const float2 mia = s_mi[ka & (L - 1)];
            const float2 mic = s_mi[kc & (L - 1)];
            const float ca = mia.y * INV_SQRT_2PI;
            const float cc = mic.y * INV_SQRT_2PI;
            #pragma unroll
            for (int h = 0; h < 4; ++h) {
                const float tf = tf0 + (float)(16 * h);
                const float ua = (tf - mia.x) * mia.y;
                const float uc = (tf - mic.x) * mic.y;
                float pa = __expf(-0.5f * ua * ua) * ca;
                float pc = __expf(-0.5f * uc * uc) * cc;
                pa = (ka <= mx) ? pa : 0.f;
                pc = (kc <= mx) ? pc : 0.f;
                ps[h] += pa + pc;
                asm("v_cvt_pk_bf16_f32 %0, %1, %2" : "=v"(A[h].u[jp]) : "v"(pa), "v"(pc));
            }
        }

        // B fragments: ONE gather, shared by all 4 halves
        BFrag B0, B1, B2, B3;
        #pragma unroll
        for (int jp = 0; jp < 4; ++jp) {
            const int ka = min(k0 + 2 * jp,     L - 1);   // p==0 past mx: garbage*0 == 0
            const int kc = min(k0 + 2 * jp + 1, L - 1);
            const float* ra = tbp + (size_t)ka * 256;
            const float* rc = tbp + (size_t)kc * 256;
            const float b0 = ra[0], b1 = ra[16], b2 = ra[32], b3 = ra[48];
            const float c0 = rc[0], c1 = rc[16], c2 = rc[32], c3 = rc[48];
            asm("v_cvt_pk_bf16_f32 %0, %1, %2" : "=v"(B0.u[jp]) : "v"(b0), "v"(c0));
            asm("v_cvt_pk_bf16_f32 %0, %1, %2" : "=v"(B1.u[jp]) : "v"(b1), "v"(c1));
            asm("v_cvt_pk_bf16_f32 %0, %1, %2" : "=v"(B2.u[jp]) : "v"(b2), "v"(c2));
            asm("v_cvt_pk_bf16_f32 %0, %1, %2" : "=v"(B3.u[jp]) : "v"(b3), "v"(c3));
        }

        #pragma unroll
        for (int h = 0; h < 4; ++h) {
            acc[h][0] = __builtin_amdgcn_mfma_f32_16x16x32_bf16(A[h].h, B0.h, acc[h][0], 0, 0, 0);
            acc[h][1] = __builtin_amdgcn_mfma_f32_16x16x32_bf16(A[h].h, B1.h, acc[h][1], 0, 0, 0);
            acc[h][2] = __builtin_amdgcn_mfma_f32_16x16x32_bf16(A[h].h, B2.h, acc[h][2], 0, 0, 0);
            acc[h][3] = __builtin_amdgcn_mfma_f32_16x16x32_bf16(A[h].h, B3.h, acc[h][3], 0, 0, 0);
        }
    }

    // ---- epilogue per half: shuffle-reduced denominators, normalize, store ----
    const int trow = g << 2;
    #pragma unroll
    for (int h = 0; h < 4; ++h) {
        float p = ps[h];
        p += __shfl_xor(p, 16, 64);
        p += __shfl_xor(p, 32, 64);
        const float rn = 1.0f / (p + EPS);   // lane (g,mrow): denom for t = t0+mrow

        const float rr0 = __shfl(rn, trow + 0, 64);
        const float rr1 = __shfl(rn, trow + 1, 64);
        const float rr2 = __shfl(rn, trow + 2, 64);
        const float rr3 = __shfl(rn, trow + 3, 64);

        const int t0 = tbase0 + (h << 4);
        float* ob = out + ((size_t)b * T + t0 + trow) * 256 + (wid << 6) + mrow;
        if (t0 + trow + 3 < T) {
            ob[0*256 +  0] = acc[h][0][0] * rr0;  ob[1*256 +  0] = acc[h][0][1] * rr1;
            ob[2*256 +  0] = acc[h][0][2] * rr2;  ob[3*256 +  0] = acc[h][0][3] * rr3;
            ob[0*256 + 16] = acc[h][1][0] * rr0;  ob[1*256 + 16] = acc[h][1][1] * rr1;
            ob[2*256 + 16] = acc[h][1][2] * rr2;  ob[3*256 + 16] = acc[h][1][3] * rr3;
            ob[0*256 + 32] = acc[h][2][0] * rr0;  ob[1*256 + 32] = acc[h][2][1] * rr1;
            ob[2*256 + 32] = acc[h][2][2] * rr2;  ob[3*256 + 32] = acc[h][2][3] * rr3;
            ob[0*256 + 48] = acc[h][3][0] * rr0;  ob[1*256 + 48] = acc[h][3][1] * rr1;
            ob[2*256 + 48] = acc[h][3][2] * rr2;  ob[3*256 + 48] = acc[h][3][3] * rr3;
        }
    }
}

extern "C" void kernel_launch(void* const* d_in, const int* in_sizes, int n_in,
                              void* d_out, int out_size, void* d_ws, size_t ws_size,
                              hipStream_t stream) {
    const int*   durs = (const int*)d_in[1];
    const float* text = (const float*)d_in[0];
    float*       out  = (float*)d_out;

    const int BL = in_sizes[1];        // B * L
    const int D  = in_sizes[0] / BL;   // 256
    const int B  = BL / L;             // 16
    const int T  = out_size / (B * D); // 2048
    const int tilesPerB = (T + BLOCK_TT - 1) / BLOCK_TT;   // 32
    const int nwg = B * tilesPerB;     // 512

    ge_mfma<<<dim3(nwg), dim3(NTHREADS), 0, stream>>>(durs, text, out, B, T, tilesPerB, nwg);
}